// Round 4
// baseline (112.155 us; speedup 1.0000x reference)
//
#include <hip/hip_runtime.h>
#include <hip/hip_bf16.h>
#include <math.h>

// DiscretisedBNF loss, MI355X gfx950.
// R17: 3 -> 2 dispatches. Budget model (closes within noise): timed path ~= 2x
//      268MB poison fills (~87us, HBM-write-bound harness fixed cost) + our
//      kernels (~11us) + boundaries (~5us each). In-kernel tuning proven ~neutral
//      (R14, R16); dispatch count is the only >us lever left (R15: -5.4us/disp).
//      Change: prep_k fused into gemm1's A-staging. Each block loads x/noise f32
//      granules and computes A = g*x + g*(1-g)*noise in-register right before the
//      ds_write (per-thread row constants g,gom hoisted out of the K-loop). Same
//      fmaf/cvt sequence as prep_k => bit-identical h. x/noise redundant re-reads
//      (32MB logical) are L3-served (2MB working set) - R9's objection was against
//      the old 128MB structure. out-zero moved to K1 block 0.
// Structure: gemm1+prep+leaky(h) -> gemm2+loss. 32x32 tile, 4 waves 2x2, BK=64,
//      depth-4 register ring over 2-buffer LDS, ONE raw s_barrier per K-step.
// Abel summation (k=127 edge kept un-saturated):
//   pO = (125/256)(1+erf(z_127)) - 126/128 - (1/128) sum_{k=1..126} erf(z_k),
//   z_k = (k/64 - 1 - mu_x) / (sigma*sqrt(2)).
// Interior sum via Euler-Maclaurin midpoint (O(1)); a>1 -> direct sum (<=7 terms).
// Ledger: coop grid.sync ~60us (R11); splitK atomics regress (R12); 2-phase
// pipeline alone neutral (R14); 5->3 fusion -10.8us (R15); 2x occupancy + BK=64
// only -2us (R16). Harness poison fills (~43.5us each) are fixed cost.

typedef __bf16 bf16_t;
typedef __bf16 bf16x8 __attribute__((ext_vector_type(8)));
typedef __bf16 bf16x4 __attribute__((ext_vector_type(4)));
typedef float  f32x4  __attribute__((ext_vector_type(4)));
typedef float  f32x8  __attribute__((ext_vector_type(8)));

#define LDK2 72  // LDS row stride in bf16 for BK=64 (64 + 8 pad) = 36 dwords
#define L2S -5.6438561897747248f  // log2(0.02)

// Abramowitz-Stegun 7.1.26, |abs err| <= 1.5e-7, branch-free full-range.
__device__ __forceinline__ float erf_f(float x) {
  float ax = __builtin_fabsf(x);
  float t = __builtin_amdgcn_rcpf(fmaf(0.3275911f, ax, 1.0f));
  float p = fmaf(fmaf(fmaf(fmaf(1.061405429f, t, -1.453152027f), t, 1.421413741f),
                      t, -0.284496736f), t, 0.254829592f);
  p *= t;
  float e = __expf(-ax * ax);
  float r = fmaf(-p, e, 1.0f);
  return __builtin_copysignf(r, x);
}

// ---- K2 GEMM inner loop (bf16 A from global) ------------------------------
// Block tile 32(m) x 32(n virtual), BK=64, 4 waves as 2x2 of 16x16 frags.
// Depth-4 register ring over 2-buffer LDS; ONE raw s_barrier per K-step.
// Safety: DS ops retire in-order per wave, so the lgkmcnt(0) before barrier k+1
// also retires phase k's ds_reads; buffer[cur] is only rewritten at k+2.
#define GSTEP(ASB, BSB, AR, BR, TILE, PF)                                        \
  {                                                                              \
    *(bf16x8*)(&ASB[arow * LDK2 + akg8]) = AR;                                   \
    bf16x8 bv_;                                                                  \
    bv_[0] = (__bf16)BR[0]; bv_[1] = (__bf16)BR[1];                              \
    bv_[2] = (__bf16)BR[2]; bv_[3] = (__bf16)BR[3];                              \
    bv_[4] = (__bf16)BR[4]; bv_[5] = (__bf16)BR[5];                              \
    bv_[6] = (__bf16)BR[6]; bv_[7] = (__bf16)BR[7];                              \
    *(bf16x8*)(&BSB[bn * LDK2 + bkg8]) = bv_;                                    \
    if (PF) {                                                                    \
      AR = *(const bf16x8*)(Ap + ((TILE) + 4) * 64);                             \
      const float* wp_ = Wp0 + (size_t)((TILE) + 4) * 64 * 2048;                 \
      BR[0] = wp_[0];        BR[1] = wp_[2048];                                  \
      BR[2] = wp_[4096];     BR[3] = wp_[6144];                                  \
      BR[4] = wp_[8192];     BR[5] = wp_[10240];                                 \
      BR[6] = wp_[12288];    BR[7] = wp_[14336];                                 \
    }                                                                            \
    asm volatile("s_waitcnt lgkmcnt(0)" ::: "memory");                           \
    __builtin_amdgcn_s_barrier();                                                \
    __builtin_amdgcn_sched_barrier(0);                                           \
    {                                                                            \
      bf16x8 aF0_ = *(const bf16x8*)(&ASB[arr]);                                 \
      bf16x8 bF0_ = *(const bf16x8*)(&BSB[brr]);                                 \
      acc = __builtin_amdgcn_mfma_f32_16x16x32_bf16(aF0_, bF0_, acc, 0, 0, 0);   \
      bf16x8 aF1_ = *(const bf16x8*)(&ASB[arr + 32]);                            \
      bf16x8 bF1_ = *(const bf16x8*)(&BSB[brr + 32]);                            \
      acc = __builtin_amdgcn_mfma_f32_16x16x32_bf16(aF1_, bF1_, acc, 0, 0, 0);   \
    }                                                                            \
  }

__device__ __forceinline__ void gemm_loop(
    const bf16_t* __restrict__ Ap, const float* __restrict__ Wp0,
    bf16_t* __restrict__ As0, bf16_t* __restrict__ As1,
    bf16_t* __restrict__ Bs0, bf16_t* __restrict__ Bs1,
    int arow, int akg8, int bn, int bkg8, int arr, int brr,
    int Ktiles, f32x4& acc) {
  bf16x8 aR0, aR1, aR2, aR3;
  f32x8 bR0, bR1, bR2, bR3;
  aR0 = *(const bf16x8*)(Ap);
  aR1 = *(const bf16x8*)(Ap + 64);
  aR2 = *(const bf16x8*)(Ap + 128);
  aR3 = *(const bf16x8*)(Ap + 192);
  {
    const float* w_ = Wp0;
    bR0[0] = w_[0];     bR0[1] = w_[2048];  bR0[2] = w_[4096];  bR0[3] = w_[6144];
    bR0[4] = w_[8192];  bR0[5] = w_[10240]; bR0[6] = w_[12288]; bR0[7] = w_[14336];
    w_ = Wp0 + (size_t)64 * 2048;
    bR1[0] = w_[0];     bR1[1] = w_[2048];  bR1[2] = w_[4096];  bR1[3] = w_[6144];
    bR1[4] = w_[8192];  bR1[5] = w_[10240]; bR1[6] = w_[12288]; bR1[7] = w_[14336];
    w_ = Wp0 + (size_t)128 * 2048;
    bR2[0] = w_[0];     bR2[1] = w_[2048];  bR2[2] = w_[4096];  bR2[3] = w_[6144];
    bR2[4] = w_[8192];  bR2[5] = w_[10240]; bR2[6] = w_[12288]; bR2[7] = w_[14336];
    w_ = Wp0 + (size_t)192 * 2048;
    bR3[0] = w_[0];     bR3[1] = w_[2048];  bR3[2] = w_[4096];  bR3[3] = w_[6144];
    bR3[4] = w_[8192];  bR3[5] = w_[10240]; bR3[6] = w_[12288]; bR3[7] = w_[14336];
  }
  for (int kt = 0; kt < Ktiles; kt += 4) {
    GSTEP(As0, Bs0, aR0, bR0, kt,     kt + 4 < Ktiles)
    GSTEP(As1, Bs1, aR1, bR1, kt + 1, kt + 5 < Ktiles)
    GSTEP(As0, Bs0, aR2, bR2, kt + 2, kt + 6 < Ktiles)
    GSTEP(As1, Bs1, aR3, bR3, kt + 3, kt + 7 < Ktiles)
  }
}

// ---- K1 GEMM inner loop (A computed from x,noise on the fly) --------------
// Identical schedule; A-ring holds raw f32 x/noise granules (2x float4 each),
// converted with the prep_k fmaf/cvt sequence right before ds_write.
#define GSTEP1(ASB, BSB, XA, XB, NA, NB, BR, TILE, PF)                           \
  {                                                                              \
    bf16x8 av_;                                                                  \
    av_[0] = (__bf16)fmaf(gom, NA.x, g * XA.x);                                  \
    av_[1] = (__bf16)fmaf(gom, NA.y, g * XA.y);                                  \
    av_[2] = (__bf16)fmaf(gom, NA.z, g * XA.z);                                  \
    av_[3] = (__bf16)fmaf(gom, NA.w, g * XA.w);                                  \
    av_[4] = (__bf16)fmaf(gom, NB.x, g * XB.x);                                  \
    av_[5] = (__bf16)fmaf(gom, NB.y, g * XB.y);                                  \
    av_[6] = (__bf16)fmaf(gom, NB.z, g * XB.z);                                  \
    av_[7] = (__bf16)fmaf(gom, NB.w, g * XB.w);                                  \
    *(bf16x8*)(&ASB[arow * LDK2 + akg8]) = av_;                                  \
    bf16x8 bv_;                                                                  \
    bv_[0] = (__bf16)BR[0]; bv_[1] = (__bf16)BR[1];                              \
    bv_[2] = (__bf16)BR[2]; bv_[3] = (__bf16)BR[3];                              \
    bv_[4] = (__bf16)BR[4]; bv_[5] = (__bf16)BR[5];                              \
    bv_[6] = (__bf16)BR[6]; bv_[7] = (__bf16)BR[7];                              \
    *(bf16x8*)(&BSB[bn * LDK2 + bkg8]) = bv_;                                    \
    if (PF) {                                                                    \
      XA = *(const float4*)(Xp + ((TILE) + 4) * 64);                             \
      XB = *(const float4*)(Xp + ((TILE) + 4) * 64 + 4);                         \
      NA = *(const float4*)(Np + ((TILE) + 4) * 64);                             \
      NB = *(const float4*)(Np + ((TILE) + 4) * 64 + 4);                         \
      const float* wp_ = Wp0 + (size_t)((TILE) + 4) * 64 * 2048;                 \
      BR[0] = wp_[0];        BR[1] = wp_[2048];                                  \
      BR[2] = wp_[4096];     BR[3] = wp_[6144];                                  \
      BR[4] = wp_[8192];     BR[5] = wp_[10240];                                 \
      BR[6] = wp_[12288];    BR[7] = wp_[14336];                                 \
    }                                                                            \
    asm volatile("s_waitcnt lgkmcnt(0)" ::: "memory");                           \
    __builtin_amdgcn_s_barrier();                                                \
    __builtin_amdgcn_sched_barrier(0);                                           \
    {                                                                            \
      bf16x8 aF0_ = *(const bf16x8*)(&ASB[arr]);                                 \
      bf16x8 bF0_ = *(const bf16x8*)(&BSB[brr]);                                 \
      acc = __builtin_amdgcn_mfma_f32_16x16x32_bf16(aF0_, bF0_, acc, 0, 0, 0);   \
      bf16x8 aF1_ = *(const bf16x8*)(&ASB[arr + 32]);                            \
      bf16x8 bF1_ = *(const bf16x8*)(&BSB[brr + 32]);                            \
      acc = __builtin_amdgcn_mfma_f32_16x16x32_bf16(aF1_, bF1_, acc, 0, 0, 0);   \
    }                                                                            \
  }

// h = leaky((g*x + g*(1-g)*noise) @ W1[0:1024,:] + t*W1[1024,:] + b1), bf16.
// grid (64 n, 8 m) = 512 blocks; block: 32 rows x 32 cols, K=1024 (16 tiles of 64).
// Block 0 also zeroes the loss accumulator (consumed next dispatch).
__global__ __launch_bounds__(256, 2)
void gemm1h_k(const float* __restrict__ x, const float* __restrict__ noise,
              const float* __restrict__ W, const float* __restrict__ b1,
              const float* __restrict__ t, bf16_t* __restrict__ h,
              float* __restrict__ out) {
  if (blockIdx.x == 0 && blockIdx.y == 0 && threadIdx.x == 0) *out = 0.0f;
  __shared__ bf16_t As0[32 * LDK2], As1[32 * LDK2];
  __shared__ bf16_t Bs0[32 * LDK2], Bs1[32 * LDK2];
  int tid = threadIdx.x;
  int lane = tid & 63, wave = tid >> 6;
  int wr = wave & 1, wc = wave >> 1;    // 2x2 wave grid: rows wr*16, cols wc*16
  int n0 = blockIdx.x * 32, m0 = blockIdx.y * 32;
  int arow = tid >> 3, akg8 = (tid & 7) * 8;  // A staging: row, 16B granule
  int bn = tid & 31, bkg8 = (tid >> 5) * 8;   // B staging: col, k-octet
  int fm = lane & 15, kq = lane >> 4;         // fragment lane decode
  int arr = (wr * 16 + fm) * LDK2 + kq * 8;
  int brr = (wc * 16 + fm) * LDK2 + kq * 8;

  // per-thread row constants for the fused prep (same math as old prep_k)
  float tvr = t[m0 + arow];
  float pr = exp2f(2.0f * tvr * L2S);      // 1-gamma
  float g = 1.0f - pr, gom = g * pr;       // gamma, gamma*(1-gamma)

  const float* Xp = x + (size_t)(m0 + arow) * 1024 + akg8;
  const float* Np = noise + (size_t)(m0 + arow) * 1024 + akg8;
  const float* Wp0 = W + (size_t)(bkg8 >> 3) * 8 * 2048 + n0 + bn;

  f32x4 acc = (f32x4)0.0f;
  {
    float4 xA0, xB0, nA0, nB0, xA1, xB1, nA1, nB1;
    float4 xA2, xB2, nA2, nB2, xA3, xB3, nA3, nB3;
    f32x8 bR0, bR1, bR2, bR3;
    xA0 = *(const float4*)(Xp);        xB0 = *(const float4*)(Xp + 4);
    nA0 = *(const float4*)(Np);        nB0 = *(const float4*)(Np + 4);
    xA1 = *(const float4*)(Xp + 64);   xB1 = *(const float4*)(Xp + 68);
    nA1 = *(const float4*)(Np + 64);   nB1 = *(const float4*)(Np + 68);
    xA2 = *(const float4*)(Xp + 128);  xB2 = *(const float4*)(Xp + 132);
    nA2 = *(const float4*)(Np + 128);  nB2 = *(const float4*)(Np + 132);
    xA3 = *(const float4*)(Xp + 192);  xB3 = *(const float4*)(Xp + 196);
    nA3 = *(const float4*)(Np + 192);  nB3 = *(const float4*)(Np + 196);
    {
      const float* w_ = Wp0;
      bR0[0] = w_[0];     bR0[1] = w_[2048];  bR0[2] = w_[4096];  bR0[3] = w_[6144];
      bR0[4] = w_[8192];  bR0[5] = w_[10240]; bR0[6] = w_[12288]; bR0[7] = w_[14336];
      w_ = Wp0 + (size_t)64 * 2048;
      bR1[0] = w_[0];     bR1[1] = w_[2048];  bR1[2] = w_[4096];  bR1[3] = w_[6144];
      bR1[4] = w_[8192];  bR1[5] = w_[10240]; bR1[6] = w_[12288]; bR1[7] = w_[14336];
      w_ = Wp0 + (size_t)128 * 2048;
      bR2[0] = w_[0];     bR2[1] = w_[2048];  bR2[2] = w_[4096];  bR2[3] = w_[6144];
      bR2[4] = w_[8192];  bR2[5] = w_[10240]; bR2[6] = w_[12288]; bR2[7] = w_[14336];
      w_ = Wp0 + (size_t)192 * 2048;
      bR3[0] = w_[0];     bR3[1] = w_[2048];  bR3[2] = w_[4096];  bR3[3] = w_[6144];
      bR3[4] = w_[8192];  bR3[5] = w_[10240]; bR3[6] = w_[12288]; bR3[7] = w_[14336];
    }
    for (int kt = 0; kt < 16; kt += 4) {
      GSTEP1(As0, Bs0, xA0, xB0, nA0, nB0, bR0, kt,     kt + 4 < 16)
      GSTEP1(As1, Bs1, xA1, xB1, nA1, nB1, bR1, kt + 1, kt + 5 < 16)
      GSTEP1(As0, Bs0, xA2, xB2, nA2, nB2, bR2, kt + 2, kt + 6 < 16)
      GSTEP1(As1, Bs1, xA3, xB3, nA3, nB3, bR3, kt + 3, kt + 7 < 16)
    }
  }

  // epilogue: C/D layout col=lane&15, row=(lane>>4)*4+reg [m89-verified]
  int col = n0 + wc * 16 + fm;
  float wl = W[(size_t)1024 * 2048 + col];
  float bb = b1[col];
#pragma unroll
  for (int e = 0; e < 4; ++e) {
    int row = m0 + wr * 16 + kq * 4 + e;
    float tv = t[row];
    float v = acc[e] + tv * wl + bb;
    v = v >= 0.f ? v : 0.01f * v;
    h[(size_t)row * 2048 + col] = (__bf16)v;
  }
}

// out2 = h @ W2 + b2 with virtual cols {d..d+15} u {1024+d..1024+d+15}:
// wc=0 waves accumulate mu_eps cols, wc=1 waves ln_sig cols; 2KB LDS exchange
// pairs them; loss on wc=0 half; one atomicAdd per block.
// grid (64 n, 8 m) = 512 blocks; block 32 rows x (16+16) cols, K=2048 (32 tiles).
__global__ __launch_bounds__(256, 2)
void gemm2loss_k(const bf16_t* __restrict__ A, const float* __restrict__ W,
                 const float* __restrict__ b2, const float* __restrict__ t,
                 const float* __restrict__ x, const float* __restrict__ noise,
                 float* __restrict__ out) {
  __shared__ bf16_t As0[32 * LDK2], As1[32 * LDK2];
  __shared__ bf16_t Bs0[32 * LDK2], Bs1[32 * LDK2];
  __shared__ float lgbuf[32][17];
  __shared__ float red[4];
  int tid = threadIdx.x;
  int lane = tid & 63, wave = tid >> 6;
  int wr = wave & 1, wc = wave >> 1;
  int n0 = blockIdx.x * 16, m0 = blockIdx.y * 32;
  int arow = tid >> 3, akg8 = (tid & 7) * 8;
  int bn = tid & 31, bkg8 = (tid >> 5) * 8;
  int fm = lane & 15, kq = lane >> 4;
  int arr = (wr * 16 + fm) * LDK2 + kq * 8;
  int brr = (wc * 16 + fm) * LDK2 + kq * 8;

  const bf16_t* Ap = A + (size_t)(m0 + arow) * 2048 + akg8;
  // dual-panel column map: bn 0..15 -> me cols n0+bn, bn 16..31 -> lg cols 1024+n0+bn-16
  int bcol = n0 + (bn & 15) + ((bn >> 4) << 10);
  const float* Wp0 = W + (size_t)(bkg8 >> 3) * 8 * 2048 + bcol;

  f32x4 acc = (f32x4)0.0f;   // wc=0: mu_eps frag; wc=1: ln_sig frag
  gemm_loop(Ap, Wp0, As0, As1, Bs0, Bs1, arow, akg8, bn, bkg8, arr, brr,
            32, acc);

  // pair (me, lg) across the wc halves through LDS
  if (wc == 1) {
#pragma unroll
    for (int e = 0; e < 4; ++e)
      lgbuf[wr * 16 + kq * 4 + e][fm] = acc[e];
  }
  __syncthreads();

  float lsum = 0.0f;
  if (wc == 0) {
    int d = n0 + fm;
    float bme = b2[d], blg = b2[1024 + d];
#pragma unroll
    for (int e = 0; e < 4; ++e) {
      int row = m0 + wr * 16 + kq * 4 + e;
      float tv = t[row];
      float om = exp2f(2.0f * tv * L2S);       // 1-gamma
      float gamma = 1.0f - om;
      float rq = sqrtf(om / gamma);
      float w = 1.0f / om;                     // SIGMA1^(-2t)
      bool lowt = tv < 1e-10f;
      float me = acc[e] + bme;
      float lg = lgbuf[wr * 16 + kq * 4 + e][fm] + blg;
      float xs = x[(size_t)row * 1024 + d], ns = noise[(size_t)row * 1024 + d];

      float mu_x = xs + om * ns - rq * me;     // mu/gamma - r*mu_eps
      float sig = rq * __expf(lg);
      if (lowt) { mu_x = 0.f; sig = 1.f; }
      float invs = 0.70710678118654752f / sig; // 1/(sigma*sqrt(2))
      float a = invs * 0.015625f;              // z step per k
      float c0 = (1.f + mu_x) * invs;          // z_k = a*k - c0
      // window |z|<3.5 for the k=1..126 interior sum; saturated tails exact
      float m64 = 64.f * (1.f + mu_x);
      float wdt = 316.78383797157331f * sig;   // 3.5/a = 224*sqrt(2)*sig
      float lo = m64 - wdt, hi = m64 + wdt;
      int klo = (lo < 1.f) ? 1 : ((lo > 126.f) ? 127 : (int)ceilf(lo));
      int khi = (hi < 1.f) ? 0 : ((hi > 126.f) ? 126 : (int)floorf(hi));
      float ss = (float)(126 - khi) - (float)(klo - 1);
      if (khi >= klo) {
        if (a <= 1.0f) {
          // Euler-Maclaurin midpoint: sum ~ (1/a)[G(zb)-G(za)] - (a/(12 sqrt(pi)))(eb-ea)
          float za = fmaf(a, (float)klo - 0.5f, -c0);
          float zb = fmaf(a, (float)khi + 0.5f, -c0);
          const float ISP = 0.56418958354775628f;  // 1/sqrt(pi)
          float ea = __expf(-za * za), eb = __expf(-zb * zb);
          float Ga = fmaf(za, erf_f(za), ISP * ea);
          float Gb = fmaf(zb, erf_f(zb), ISP * eb);
          float S = (Gb - Ga) * __builtin_amdgcn_rcpf(a)
                  - a * 0.047015889f * (eb - ea);  // 1/(12*sqrt(pi))
          ss += S;
        } else {
          for (int k = klo; k <= khi; ++k) ss += erf_f(fmaf(a, (float)k, -c0));
        }
      }
      float z127 = fmaf(a, 127.f, -c0);
      float pO = fmaf(0.48828125f, 1.f + erf_f(z127),
                      fmaf(-0.0078125f, ss, -0.984375f));
      float df = xs - pO;
      lsum += w * df * df;
    }
  }
#pragma unroll
  for (int off = 32; off > 0; off >>= 1) lsum += __shfl_down(lsum, off, 64);
  if ((tid & 63) == 0) red[wave] = lsum;
  __syncthreads();
  if (tid == 0) {
    const float SCALE = 3.9120230054281461f / 262144.0f;  // -ln(0.02)/(B*D)
    atomicAdd(out, (red[0] + red[1] + red[2] + red[3]) * SCALE);
  }
}

extern "C" void kernel_launch(void* const* d_in, const int* in_sizes, int n_in,
                              void* d_out, int out_size, void* d_ws, size_t ws_size,
                              hipStream_t stream) {
  const float* x     = (const float*)d_in[0];
  const float* t     = (const float*)d_in[1];
  const float* noise = (const float*)d_in[2];
  const float* W1    = (const float*)d_in[3];
  const float* b1    = (const float*)d_in[4];
  const float* W2    = (const float*)d_in[5];
  const float* b2    = (const float*)d_in[6];
  float* out = (float*)d_out;

  // ws layout (1 MB live): h bf16
  bf16_t* h = (bf16_t*)d_ws;

  gemm1h_k<<<dim3(64, 8), 256, 0, stream>>>(x, noise, W1, b1, t, h, out);
  gemm2loss_k<<<dim3(64, 8), 256, 0, stream>>>(h, W2, b2, t, x, noise, out);
}

// Round 5
// 106.006 us; speedup vs baseline: 1.0580x; 1.0580x over previous
//
#include <hip/hip_runtime.h>
#include <hip/hip_bf16.h>
#include <math.h>

// DiscretisedBNF loss, MI355X gfx950.
// R18: revert R17's prep-fusion (+1.8us: 128MB x/noise L2 re-reads; R9 was right,
//      smaller constant) back to R16's 3-dispatch structure, then cut gemm2's
//      dominant L2 term: logical traffic = M*N*K*(1/BN+1/BM); BM 32->64 halves the
//      f32 B-panel re-reads (134->67 MB). R15 tried BM=64 with 4 waves (1 wave/SIMD,
//      latency-dead); here 512 threads/block = 8 waves (4m x 2n) -> 256 blocks =
//      1 block/CU but 2 waves/SIMD = R16's wave-TLP with R15's traffic profile.
// Structure: prep(A1 bf16, zero out) -> gemm1+leaky(h) [R16 verbatim] ->
//      gemm2(BM=64, 512thr)+loss. BK=64, depth-4 register ring over 2-buffer LDS,
//      ONE raw s_barrier per K-step everywhere.
// Abel summation (k=127 edge kept un-saturated):
//   pO = (125/256)(1+erf(z_127)) - 126/128 - (1/128) sum_{k=1..126} erf(z_k),
//   z_k = (k/64 - 1 - mu_x) / (sigma*sqrt(2)).
// Interior sum via Euler-Maclaurin midpoint (O(1)); a>1 -> direct sum (<=7 terms).
// Ledger: coop grid.sync ~60us (R11); splitK atomics regress (R12); 2-phase
// pipeline alone neutral (R14); fusion -10.8us = partial-traffic removal, NOT
// boundaries (R15/R17); 2x wave-TLP -2us (R16); prep-in-gemm fusion +1.8us (R17).
// Harness poison fills (~2x 256MiB @ ~44us) are fixed cost inside the timed path;
// controllable region ~22us (kernels + launch), floor est. ~12us.

typedef __bf16 bf16_t;
typedef __bf16 bf16x8 __attribute__((ext_vector_type(8)));
typedef __bf16 bf16x4 __attribute__((ext_vector_type(4)));
typedef float  f32x4  __attribute__((ext_vector_type(4)));
typedef float  f32x8  __attribute__((ext_vector_type(8)));

#define LDK2 72  // LDS row stride in bf16 for BK=64 (64 + 8 pad) = 36 dwords
#define L2S -5.6438561897747248f  // log2(0.02)

// Abramowitz-Stegun 7.1.26, |abs err| <= 1.5e-7, branch-free full-range.
__device__ __forceinline__ float erf_f(float x) {
  float ax = __builtin_fabsf(x);
  float t = __builtin_amdgcn_rcpf(fmaf(0.3275911f, ax, 1.0f));
  float p = fmaf(fmaf(fmaf(fmaf(1.061405429f, t, -1.453152027f), t, 1.421413741f),
                      t, -0.284496736f), t, 0.254829592f);
  p *= t;
  float e = __expf(-ax * ax);
  float r = fmaf(-p, e, 1.0f);
  return __builtin_copysignf(r, x);
}

// block b handles row b (1024 elems, 256 thr x 4): A1 = gamma*x + gamma*(1-gamma)*noise.
// Also zeroes the loss accumulator (consumed 2 dispatches later by gemm2loss_k).
__global__ __launch_bounds__(256, 2)
void prep_k(const float* __restrict__ x, const float* __restrict__ noise,
            const float* __restrict__ t, bf16_t* __restrict__ A1,
            float* __restrict__ out) {
  if (blockIdx.x == 0 && threadIdx.x == 0) *out = 0.0f;
  int b = blockIdx.x;
  float tv = t[b];
  float p = exp2f(2.0f * tv * L2S);        // 1-gamma = 0.02^(2t)
  float g = 1.0f - p, gom = g * p;         // gamma, gamma*(1-gamma)
  int e = (b * 256 + threadIdx.x) * 4;
  float4 xv = *(const float4*)(x + e);
  float4 nv = *(const float4*)(noise + e);
  bf16x4 o;
  o[0] = (__bf16)fmaf(gom, nv.x, g * xv.x);
  o[1] = (__bf16)fmaf(gom, nv.y, g * xv.y);
  o[2] = (__bf16)fmaf(gom, nv.z, g * xv.z);
  o[3] = (__bf16)fmaf(gom, nv.w, g * xv.w);
  *(bf16x4*)(A1 + e) = o;
}

// ---- gemm1 inner loop (256 thr, BM=32, 8 f32/thread B-staging) ------------
// Depth-4 register ring over 2-buffer LDS; ONE raw s_barrier per K-step.
// Safety: DS ops retire in-order per wave, so the lgkmcnt(0) before barrier k+1
// also retires phase k's ds_reads; buffer[cur] is only rewritten at k+2.
#define GSTEP(ASB, BSB, AR, BR, TILE, PF)                                        \
  {                                                                              \
    *(bf16x8*)(&ASB[arow * LDK2 + akg8]) = AR;                                   \
    bf16x8 bv_;                                                                  \
    bv_[0] = (__bf16)BR[0]; bv_[1] = (__bf16)BR[1];                              \
    bv_[2] = (__bf16)BR[2]; bv_[3] = (__bf16)BR[3];                              \
    bv_[4] = (__bf16)BR[4]; bv_[5] = (__bf16)BR[5];                              \
    bv_[6] = (__bf16)BR[6]; bv_[7] = (__bf16)BR[7];                              \
    *(bf16x8*)(&BSB[bn * LDK2 + bkg8]) = bv_;                                    \
    if (PF) {                                                                    \
      AR = *(const bf16x8*)(Ap + ((TILE) + 4) * 64);                             \
      const float* wp_ = Wp0 + (size_t)((TILE) + 4) * 64 * 2048;                 \
      BR[0] = wp_[0];        BR[1] = wp_[2048];                                  \
      BR[2] = wp_[4096];     BR[3] = wp_[6144];                                  \
      BR[4] = wp_[8192];     BR[5] = wp_[10240];                                 \
      BR[6] = wp_[12288];    BR[7] = wp_[14336];                                 \
    }                                                                            \
    asm volatile("s_waitcnt lgkmcnt(0)" ::: "memory");                           \
    __builtin_amdgcn_s_barrier();                                                \
    __builtin_amdgcn_sched_barrier(0);                                           \
    {                                                                            \
      bf16x8 aF0_ = *(const bf16x8*)(&ASB[arr]);                                 \
      bf16x8 bF0_ = *(const bf16x8*)(&BSB[brr]);                                 \
      acc = __builtin_amdgcn_mfma_f32_16x16x32_bf16(aF0_, bF0_, acc, 0, 0, 0);   \
      bf16x8 aF1_ = *(const bf16x8*)(&ASB[arr + 32]);                            \
      bf16x8 bF1_ = *(const bf16x8*)(&BSB[brr + 32]);                            \
      acc = __builtin_amdgcn_mfma_f32_16x16x32_bf16(aF1_, bF1_, acc, 0, 0, 0);   \
    }                                                                            \
  }

__device__ __forceinline__ void gemm_loop(
    const bf16_t* __restrict__ Ap, const float* __restrict__ Wp0,
    bf16_t* __restrict__ As0, bf16_t* __restrict__ As1,
    bf16_t* __restrict__ Bs0, bf16_t* __restrict__ Bs1,
    int arow, int akg8, int bn, int bkg8, int arr, int brr,
    int Ktiles, f32x4& acc) {
  bf16x8 aR0, aR1, aR2, aR3;
  f32x8 bR0, bR1, bR2, bR3;
  aR0 = *(const bf16x8*)(Ap);
  aR1 = *(const bf16x8*)(Ap + 64);
  aR2 = *(const bf16x8*)(Ap + 128);
  aR3 = *(const bf16x8*)(Ap + 192);
  {
    const float* w_ = Wp0;
    bR0[0] = w_[0];     bR0[1] = w_[2048];  bR0[2] = w_[4096];  bR0[3] = w_[6144];
    bR0[4] = w_[8192];  bR0[5] = w_[10240]; bR0[6] = w_[12288]; bR0[7] = w_[14336];
    w_ = Wp0 + (size_t)64 * 2048;
    bR1[0] = w_[0];     bR1[1] = w_[2048];  bR1[2] = w_[4096];  bR1[3] = w_[6144];
    bR1[4] = w_[8192];  bR1[5] = w_[10240]; bR1[6] = w_[12288]; bR1[7] = w_[14336];
    w_ = Wp0 + (size_t)128 * 2048;
    bR2[0] = w_[0];     bR2[1] = w_[2048];  bR2[2] = w_[4096];  bR2[3] = w_[6144];
    bR2[4] = w_[8192];  bR2[5] = w_[10240]; bR2[6] = w_[12288]; bR2[7] = w_[14336];
    w_ = Wp0 + (size_t)192 * 2048;
    bR3[0] = w_[0];     bR3[1] = w_[2048];  bR3[2] = w_[4096];  bR3[3] = w_[6144];
    bR3[4] = w_[8192];  bR3[5] = w_[10240]; bR3[6] = w_[12288]; bR3[7] = w_[14336];
  }
  for (int kt = 0; kt < Ktiles; kt += 4) {
    GSTEP(As0, Bs0, aR0, bR0, kt,     kt + 4 < Ktiles)
    GSTEP(As1, Bs1, aR1, bR1, kt + 1, kt + 5 < Ktiles)
    GSTEP(As0, Bs0, aR2, bR2, kt + 2, kt + 6 < Ktiles)
    GSTEP(As1, Bs1, aR3, bR3, kt + 3, kt + 7 < Ktiles)
  }
}

// h = leaky(A1 @ W1[0:1024,:] + t*W1[1024,:] + b1), bf16.  [R16 verbatim]
// grid (64 n, 8 m) = 512 blocks; block: 32 rows x 32 cols, K=1024 (16 tiles of 64).
__global__ __launch_bounds__(256, 2)
void gemm1h_k(const bf16_t* __restrict__ A, const float* __restrict__ W,
              const float* __restrict__ b1, const float* __restrict__ t,
              bf16_t* __restrict__ h) {
  __shared__ bf16_t As0[32 * LDK2], As1[32 * LDK2];
  __shared__ bf16_t Bs0[32 * LDK2], Bs1[32 * LDK2];
  int tid = threadIdx.x;
  int lane = tid & 63, wave = tid >> 6;
  int wr = wave & 1, wc = wave >> 1;    // 2x2 wave grid: rows wr*16, cols wc*16
  int n0 = blockIdx.x * 32, m0 = blockIdx.y * 32;
  int arow = tid >> 3, akg8 = (tid & 7) * 8;  // A staging: row, 16B granule
  int bn = tid & 31, bkg8 = (tid >> 5) * 8;   // B staging: col, k-octet
  int fm = lane & 15, kq = lane >> 4;         // fragment lane decode
  int arr = (wr * 16 + fm) * LDK2 + kq * 8;
  int brr = (wc * 16 + fm) * LDK2 + kq * 8;

  const bf16_t* Ap = A + (size_t)(m0 + arow) * 1024 + akg8;
  const float* Wp0 = W + (size_t)(bkg8 >> 3) * 8 * 2048 + n0 + bn;

  f32x4 acc = (f32x4)0.0f;
  gemm_loop(Ap, Wp0, As0, As1, Bs0, Bs1, arow, akg8, bn, bkg8, arr, brr,
            16, acc);

  // epilogue: C/D layout col=lane&15, row=(lane>>4)*4+reg [m89-verified]
  int col = n0 + wc * 16 + fm;
  float wl = W[(size_t)1024 * 2048 + col];
  float bb = b1[col];
#pragma unroll
  for (int e = 0; e < 4; ++e) {
    int row = m0 + wr * 16 + kq * 4 + e;
    float tv = t[row];
    float v = acc[e] + tv * wl + bb;
    v = v >= 0.f ? v : 0.01f * v;
    h[(size_t)row * 2048 + col] = (__bf16)v;
  }
}

// ---- gemm2 inner step (512 thr, BM=64, 4 f32/thread B-staging) ------------
#define GSTEP2(ASB, BSB, AR, BR, TILE, PF)                                       \
  {                                                                              \
    *(bf16x8*)(&ASB[arow * LDK2 + akg8]) = AR;                                   \
    bf16x4 bv_;                                                                  \
    bv_[0] = (__bf16)BR[0]; bv_[1] = (__bf16)BR[1];                              \
    bv_[2] = (__bf16)BR[2]; bv_[3] = (__bf16)BR[3];                              \
    *(bf16x4*)(&BSB[bn * LDK2 + bkq4]) = bv_;                                    \
    if (PF) {                                                                    \
      AR = *(const bf16x8*)(Ap + ((TILE) + 4) * 64);                             \
      const float* wp_ = Wp0 + (size_t)((TILE) + 4) * 64 * 2048;                 \
      BR[0] = wp_[0]; BR[1] = wp_[2048]; BR[2] = wp_[4096]; BR[3] = wp_[6144];   \
    }                                                                            \
    asm volatile("s_waitcnt lgkmcnt(0)" ::: "memory");                           \
    __builtin_amdgcn_s_barrier();                                                \
    __builtin_amdgcn_sched_barrier(0);                                           \
    {                                                                            \
      bf16x8 aF0_ = *(const bf16x8*)(&ASB[arr]);                                 \
      bf16x8 bF0_ = *(const bf16x8*)(&BSB[brr]);                                 \
      acc = __builtin_amdgcn_mfma_f32_16x16x32_bf16(aF0_, bF0_, acc, 0, 0, 0);   \
      bf16x8 aF1_ = *(const bf16x8*)(&ASB[arr + 32]);                            \
      bf16x8 bF1_ = *(const bf16x8*)(&BSB[brr + 32]);                            \
      acc = __builtin_amdgcn_mfma_f32_16x16x32_bf16(aF1_, bF1_, acc, 0, 0, 0);   \
    }                                                                            \
  }

// out2 = h @ W2 + b2 with virtual cols {d..d+15} u {1024+d..1024+d+15}:
// wc=0 waves (4) accumulate mu_eps cols, wc=1 waves ln_sig cols; LDS exchange
// pairs them; loss on wc=0 half; one atomicAdd per block.
// grid (64 n, 4 m) = 256 blocks x 512 thr (8 waves, 4m x 2n): 1 block/CU,
// 2 waves/SIMD. Block 64 rows x (16+16) cols, K=2048 (32 tiles of 64).
__global__ __launch_bounds__(512, 2)
void gemm2loss_k(const bf16_t* __restrict__ A, const float* __restrict__ W,
                 const float* __restrict__ b2, const float* __restrict__ t,
                 const float* __restrict__ x, const float* __restrict__ noise,
                 float* __restrict__ out) {
  __shared__ bf16_t As0[64 * LDK2], As1[64 * LDK2];
  __shared__ bf16_t Bs0[32 * LDK2], Bs1[32 * LDK2];
  __shared__ float lgbuf[64][17];
  __shared__ float red[8];
  int tid = threadIdx.x;
  int lane = tid & 63, wave = tid >> 6;
  int wr = wave & 3, wc = wave >> 2;          // 4x2 wave grid: rows wr*16, cols wc*16
  int n0 = blockIdx.x * 16, m0 = blockIdx.y * 64;
  int arow = tid >> 3, akg8 = (tid & 7) * 8;  // A staging: row 0..63, 16B granule
  int bn = tid & 31, bkq4 = (tid >> 5) * 4;   // B staging: col 0..31, k-quad 0..15
  int fm = lane & 15, kq = lane >> 4;         // fragment lane decode
  int arr = (wr * 16 + fm) * LDK2 + kq * 8;
  int brr = (wc * 16 + fm) * LDK2 + kq * 8;

  const bf16_t* Ap = A + (size_t)(m0 + arow) * 2048 + akg8;
  // dual-panel column map: bn 0..15 -> me cols n0+bn, bn 16..31 -> lg cols 1024+n0+bn-16
  int bcol = n0 + (bn & 15) + ((bn >> 4) << 10);
  const float* Wp0 = W + (size_t)(bkq4 >> 2) * 4 * 2048 + bcol;

  f32x4 acc = (f32x4)0.0f;   // wc=0: mu_eps frag; wc=1: ln_sig frag
  {
    bf16x8 aR0, aR1, aR2, aR3;
    f32x4 bR0, bR1, bR2, bR3;
    aR0 = *(const bf16x8*)(Ap);
    aR1 = *(const bf16x8*)(Ap + 64);
    aR2 = *(const bf16x8*)(Ap + 128);
    aR3 = *(const bf16x8*)(Ap + 192);
    {
      const float* w_ = Wp0;
      bR0[0] = w_[0]; bR0[1] = w_[2048]; bR0[2] = w_[4096]; bR0[3] = w_[6144];
      w_ = Wp0 + (size_t)64 * 2048;
      bR1[0] = w_[0]; bR1[1] = w_[2048]; bR1[2] = w_[4096]; bR1[3] = w_[6144];
      w_ = Wp0 + (size_t)128 * 2048;
      bR2[0] = w_[0]; bR2[1] = w_[2048]; bR2[2] = w_[4096]; bR2[3] = w_[6144];
      w_ = Wp0 + (size_t)192 * 2048;
      bR3[0] = w_[0]; bR3[1] = w_[2048]; bR3[2] = w_[4096]; bR3[3] = w_[6144];
    }
    for (int kt = 0; kt < 32; kt += 4) {
      GSTEP2(As0, Bs0, aR0, bR0, kt,     kt + 4 < 32)
      GSTEP2(As1, Bs1, aR1, bR1, kt + 1, kt + 5 < 32)
      GSTEP2(As0, Bs0, aR2, bR2, kt + 2, kt + 6 < 32)
      GSTEP2(As1, Bs1, aR3, bR3, kt + 3, kt + 7 < 32)
    }
  }

  // pair (me, lg) across the wc halves through LDS
  if (wc == 1) {
#pragma unroll
    for (int e = 0; e < 4; ++e)
      lgbuf[wr * 16 + kq * 4 + e][fm] = acc[e];
  }
  __syncthreads();

  float lsum = 0.0f;
  if (wc == 0) {
    int d = n0 + fm;
    float bme = b2[d], blg = b2[1024 + d];
#pragma unroll
    for (int e = 0; e < 4; ++e) {
      int row = m0 + wr * 16 + kq * 4 + e;
      float tv = t[row];
      float om = exp2f(2.0f * tv * L2S);       // 1-gamma
      float gamma = 1.0f - om;
      float rq = sqrtf(om / gamma);
      float w = 1.0f / om;                     // SIGMA1^(-2t)
      bool lowt = tv < 1e-10f;
      float me = acc[e] + bme;
      float lg = lgbuf[wr * 16 + kq * 4 + e][fm] + blg;
      float xs = x[(size_t)row * 1024 + d], ns = noise[(size_t)row * 1024 + d];

      float mu_x = xs + om * ns - rq * me;     // mu/gamma - r*mu_eps
      float sig = rq * __expf(lg);
      if (lowt) { mu_x = 0.f; sig = 1.f; }
      float invs = 0.70710678118654752f / sig; // 1/(sigma*sqrt(2))
      float a = invs * 0.015625f;              // z step per k
      float c0 = (1.f + mu_x) * invs;          // z_k = a*k - c0
      // window |z|<3.5 for the k=1..126 interior sum; saturated tails exact
      float m64 = 64.f * (1.f + mu_x);
      float wdt = 316.78383797157331f * sig;   // 3.5/a = 224*sqrt(2)*sig
      float lo = m64 - wdt, hi = m64 + wdt;
      int klo = (lo < 1.f) ? 1 : ((lo > 126.f) ? 127 : (int)ceilf(lo));
      int khi = (hi < 1.f) ? 0 : ((hi > 126.f) ? 126 : (int)floorf(hi));
      float ss = (float)(126 - khi) - (float)(klo - 1);
      if (khi >= klo) {
        if (a <= 1.0f) {
          // Euler-Maclaurin midpoint: sum ~ (1/a)[G(zb)-G(za)] - (a/(12 sqrt(pi)))(eb-ea)
          float za = fmaf(a, (float)klo - 0.5f, -c0);
          float zb = fmaf(a, (float)khi + 0.5f, -c0);
          const float ISP = 0.56418958354775628f;  // 1/sqrt(pi)
          float ea = __expf(-za * za), eb = __expf(-zb * zb);
          float Ga = fmaf(za, erf_f(za), ISP * ea);
          float Gb = fmaf(zb, erf_f(zb), ISP * eb);
          float S = (Gb - Ga) * __builtin_amdgcn_rcpf(a)
                  - a * 0.047015889f * (eb - ea);  // 1/(12*sqrt(pi))
          ss += S;
        } else {
          for (int k = klo; k <= khi; ++k) ss += erf_f(fmaf(a, (float)k, -c0));
        }
      }
      float z127 = fmaf(a, 127.f, -c0);
      float pO = fmaf(0.48828125f, 1.f + erf_f(z127),
                      fmaf(-0.0078125f, ss, -0.984375f));
      float df = xs - pO;
      lsum += w * df * df;
    }
  }
#pragma unroll
  for (int off = 32; off > 0; off >>= 1) lsum += __shfl_down(lsum, off, 64);
  if ((tid & 63) == 0) red[wave] = lsum;
  __syncthreads();
  if (tid == 0) {
    const float SCALE = 3.9120230054281461f / 262144.0f;  // -ln(0.02)/(B*D)
    atomicAdd(out, (red[0] + red[1] + red[2] + red[3] +
                    red[4] + red[5] + red[6] + red[7]) * SCALE);
  }
}

extern "C" void kernel_launch(void* const* d_in, const int* in_sizes, int n_in,
                              void* d_out, int out_size, void* d_ws, size_t ws_size,
                              hipStream_t stream) {
  const float* x     = (const float*)d_in[0];
  const float* t     = (const float*)d_in[1];
  const float* noise = (const float*)d_in[2];
  const float* W1    = (const float*)d_in[3];
  const float* b1    = (const float*)d_in[4];
  const float* W2    = (const float*)d_in[5];
  const float* b2    = (const float*)d_in[6];
  float* out = (float*)d_out;

  // ws layout (1.5 MB live): A1 bf16 512 KB, h bf16 1 MB
  char* ws = (char*)d_ws;
  bf16_t* A1 = (bf16_t*)ws;
  bf16_t* h  = (bf16_t*)(ws + 524288);

  prep_k<<<256, 256, 0, stream>>>(x, noise, t, A1, out);
  gemm1h_k<<<dim3(64, 8), 256, 0, stream>>>(A1, W1, b1, t, h);
  gemm2loss_k<<<dim3(64, 4), 512, 0, stream>>>(h, W2, b2, t, x, noise, out);
}

// Round 6
// 105.015 us; speedup vs baseline: 1.0680x; 1.0094x over previous
//
#include <hip/hip_runtime.h>
#include <hip/hip_bf16.h>
#include <math.h>

// DiscretisedBNF loss, MI355X gfx950.
// R19: apply R18's proven transform (BM=64, 512 thr, 8 waves 4m x 2n) to gemm1.
//      L2-logical-traffic model (validated R18: -4.4us for gemm2): traffic =
//      M*N*K*(1/BN+1/BM); gemm1 W1 re-reads 64->32 MB. Grid (64,4)=256 blocks =
//      1 block/CU, 2 waves/SIMD (R16-proven TLP point). Per-output K-order
//      unchanged -> bit-identical (absmax 0.0). Both GEMMs share one templated
//      512-thread loop (GSTEP2 ring).
// Structure: prep(A1 bf16, zero out) -> gemm1+leaky(h) -> gemm2+loss.
//      BK=64, depth-4 register ring over 2-buffer LDS, ONE raw s_barrier/K-step.
// Abel summation (k=127 edge kept un-saturated):
//   pO = (125/256)(1+erf(z_127)) - 126/128 - (1/128) sum_{k=1..126} erf(z_k),
//   z_k = (k/64 - 1 - mu_x) / (sigma*sqrt(2)).
// Interior sum via Euler-Maclaurin midpoint (O(1)); a>1 -> direct sum (<=7 terms).
// Ledger: coop grid.sync ~60us (R11); splitK atomics regress (R12); 2-phase
// pipeline alone neutral (R14); fusion win = partial-traffic removal (R15);
// wave-TLP -2us (R16); prep-in-gemm +1.8us (R17); gemm2 BM=64/512thr -4.4us
// (R18). Harness poison fills (2x 256MiB @ ~43us) are fixed cost in the timed
// path; controllable region ~19us, floor est ~13us (W1+W2 HBM 3.8us + launches).

typedef __bf16 bf16_t;
typedef __bf16 bf16x8 __attribute__((ext_vector_type(8)));
typedef __bf16 bf16x4 __attribute__((ext_vector_type(4)));
typedef float  f32x4  __attribute__((ext_vector_type(4)));

#define LDK2 72  // LDS row stride in bf16 for BK=64 (64 + 8 pad) = 36 dwords
#define L2S -5.6438561897747248f  // log2(0.02)

// Abramowitz-Stegun 7.1.26, |abs err| <= 1.5e-7, branch-free full-range.
__device__ __forceinline__ float erf_f(float x) {
  float ax = __builtin_fabsf(x);
  float t = __builtin_amdgcn_rcpf(fmaf(0.3275911f, ax, 1.0f));
  float p = fmaf(fmaf(fmaf(fmaf(1.061405429f, t, -1.453152027f), t, 1.421413741f),
                      t, -0.284496736f), t, 0.254829592f);
  p *= t;
  float e = __expf(-ax * ax);
  float r = fmaf(-p, e, 1.0f);
  return __builtin_copysignf(r, x);
}

// block b handles row b (1024 elems, 256 thr x 4): A1 = gamma*x + gamma*(1-gamma)*noise.
// Also zeroes the loss accumulator (consumed 2 dispatches later by gemm2loss_k).
__global__ __launch_bounds__(256, 2)
void prep_k(const float* __restrict__ x, const float* __restrict__ noise,
            const float* __restrict__ t, bf16_t* __restrict__ A1,
            float* __restrict__ out) {
  if (blockIdx.x == 0 && threadIdx.x == 0) *out = 0.0f;
  int b = blockIdx.x;
  float tv = t[b];
  float p = exp2f(2.0f * tv * L2S);        // 1-gamma = 0.02^(2t)
  float g = 1.0f - p, gom = g * p;         // gamma, gamma*(1-gamma)
  int e = (b * 256 + threadIdx.x) * 4;
  float4 xv = *(const float4*)(x + e);
  float4 nv = *(const float4*)(noise + e);
  bf16x4 o;
  o[0] = (__bf16)fmaf(gom, nv.x, g * xv.x);
  o[1] = (__bf16)fmaf(gom, nv.y, g * xv.y);
  o[2] = (__bf16)fmaf(gom, nv.z, g * xv.z);
  o[3] = (__bf16)fmaf(gom, nv.w, g * xv.w);
  *(bf16x4*)(A1 + e) = o;
}

// ---- shared 512-thread GEMM inner loop (BM=64, BN=32 phys, BK=64) ---------
// 8 waves as 4m x 2n of 16x16 frags; depth-4 register ring over 2-buffer LDS;
// ONE raw s_barrier per K-step. Safety: DS ops retire in-order per wave, so
// the lgkmcnt(0) before barrier k+1 also retires phase k's ds_reads;
// buffer[cur] is only rewritten at k+2, after barrier k+1.
// A staging: thread = (row = tid>>3, 16B granule = tid&7)  [64 x 64 bf16 tile]
// B staging: thread = (col = tid&31, k-quad = tid>>5), 4 strided f32 -> bf16x4.
#define GSTEP2(ASB, BSB, AR, BR, TILE, PF)                                       \
  {                                                                              \
    *(bf16x8*)(&ASB[arow * LDK2 + akg8]) = AR;                                   \
    bf16x4 bv_;                                                                  \
    bv_[0] = (__bf16)BR[0]; bv_[1] = (__bf16)BR[1];                              \
    bv_[2] = (__bf16)BR[2]; bv_[3] = (__bf16)BR[3];                              \
    *(bf16x4*)(&BSB[bn * LDK2 + bkq4]) = bv_;                                    \
    if (PF) {                                                                    \
      AR = *(const bf16x8*)(Ap + (size_t)((TILE) + 4) * 64);                     \
      const float* wp_ = Wp0 + (size_t)((TILE) + 4) * 64 * 2048;                 \
      BR[0] = wp_[0]; BR[1] = wp_[2048]; BR[2] = wp_[4096]; BR[3] = wp_[6144];   \
    }                                                                            \
    asm volatile("s_waitcnt lgkmcnt(0)" ::: "memory");                           \
    __builtin_amdgcn_s_barrier();                                                \
    __builtin_amdgcn_sched_barrier(0);                                           \
    {                                                                            \
      bf16x8 aF0_ = *(const bf16x8*)(&ASB[arr]);                                 \
      bf16x8 bF0_ = *(const bf16x8*)(&BSB[brr]);                                 \
      acc = __builtin_amdgcn_mfma_f32_16x16x32_bf16(aF0_, bF0_, acc, 0, 0, 0);   \
      bf16x8 aF1_ = *(const bf16x8*)(&ASB[arr + 32]);                            \
      bf16x8 bF1_ = *(const bf16x8*)(&BSB[brr + 32]);                            \
      acc = __builtin_amdgcn_mfma_f32_16x16x32_bf16(aF1_, bF1_, acc, 0, 0, 0);   \
    }                                                                            \
  }

template <int KT>
__device__ __forceinline__ void g512_loop(
    const bf16_t* __restrict__ Ap, const float* __restrict__ Wp0,
    bf16_t* __restrict__ As0, bf16_t* __restrict__ As1,
    bf16_t* __restrict__ Bs0, bf16_t* __restrict__ Bs1,
    int arow, int akg8, int bn, int bkq4, int arr, int brr, f32x4& acc) {
  bf16x8 aR0, aR1, aR2, aR3;
  f32x4 bR0, bR1, bR2, bR3;
  aR0 = *(const bf16x8*)(Ap);
  aR1 = *(const bf16x8*)(Ap + 64);
  aR2 = *(const bf16x8*)(Ap + 128);
  aR3 = *(const bf16x8*)(Ap + 192);
  {
    const float* w_ = Wp0;
    bR0[0] = w_[0]; bR0[1] = w_[2048]; bR0[2] = w_[4096]; bR0[3] = w_[6144];
    w_ = Wp0 + (size_t)64 * 2048;
    bR1[0] = w_[0]; bR1[1] = w_[2048]; bR1[2] = w_[4096]; bR1[3] = w_[6144];
    w_ = Wp0 + (size_t)128 * 2048;
    bR2[0] = w_[0]; bR2[1] = w_[2048]; bR2[2] = w_[4096]; bR2[3] = w_[6144];
    w_ = Wp0 + (size_t)192 * 2048;
    bR3[0] = w_[0]; bR3[1] = w_[2048]; bR3[2] = w_[4096]; bR3[3] = w_[6144];
  }
  for (int kt = 0; kt < KT; kt += 4) {
    GSTEP2(As0, Bs0, aR0, bR0, kt,     kt + 4 < KT)
    GSTEP2(As1, Bs1, aR1, bR1, kt + 1, kt + 5 < KT)
    GSTEP2(As0, Bs0, aR2, bR2, kt + 2, kt + 6 < KT)
    GSTEP2(As1, Bs1, aR3, bR3, kt + 3, kt + 7 < KT)
  }
}

// h = leaky(A1 @ W1[0:1024,:] + t*W1[1024,:] + b1), bf16.
// grid (64 n, 4 m) = 256 blocks x 512 thr; block 64 rows x 32 cols, K=1024 (16 tiles).
__global__ __launch_bounds__(512, 2)
void gemm1h_k(const bf16_t* __restrict__ A, const float* __restrict__ W,
              const float* __restrict__ b1, const float* __restrict__ t,
              bf16_t* __restrict__ h) {
  __shared__ bf16_t As0[64 * LDK2], As1[64 * LDK2];
  __shared__ bf16_t Bs0[32 * LDK2], Bs1[32 * LDK2];
  int tid = threadIdx.x;
  int lane = tid & 63, wave = tid >> 6;
  int wr = wave & 3, wc = wave >> 2;          // 4x2 wave grid
  int n0 = blockIdx.x * 32, m0 = blockIdx.y * 64;
  int arow = tid >> 3, akg8 = (tid & 7) * 8;  // A staging: row 0..63, 16B granule
  int bn = tid & 31, bkq4 = (tid >> 5) * 4;   // B staging: col 0..31, k-quad
  int fm = lane & 15, kq = lane >> 4;         // fragment lane decode
  int arr = (wr * 16 + fm) * LDK2 + kq * 8;
  int brr = (wc * 16 + fm) * LDK2 + kq * 8;

  const bf16_t* Ap = A + (size_t)(m0 + arow) * 1024 + akg8;
  const float* Wp0 = W + (size_t)bkq4 * 2048 + n0 + bn;

  f32x4 acc = (f32x4)0.0f;
  g512_loop<16>(Ap, Wp0, As0, As1, Bs0, Bs1, arow, akg8, bn, bkq4, arr, brr, acc);

  // epilogue: C/D layout col=lane&15, row=(lane>>4)*4+reg [m89-verified]
  int col = n0 + wc * 16 + fm;
  float wl = W[(size_t)1024 * 2048 + col];
  float bb = b1[col];
#pragma unroll
  for (int e = 0; e < 4; ++e) {
    int row = m0 + wr * 16 + kq * 4 + e;
    float tv = t[row];
    float v = acc[e] + tv * wl + bb;
    v = v >= 0.f ? v : 0.01f * v;
    h[(size_t)row * 2048 + col] = (__bf16)v;
  }
}

// out2 = h @ W2 + b2 with virtual cols {d..d+15} u {1024+d..1024+d+15}:
// wc=0 waves (4) accumulate mu_eps cols, wc=1 waves ln_sig cols; LDS exchange
// pairs them; loss on wc=0 half; one atomicAdd per block.
// grid (64 n, 4 m) = 256 blocks x 512 thr; block 64 rows x (16+16) cols, K=2048.
__global__ __launch_bounds__(512, 2)
void gemm2loss_k(const bf16_t* __restrict__ A, const float* __restrict__ W,
                 const float* __restrict__ b2, const float* __restrict__ t,
                 const float* __restrict__ x, const float* __restrict__ noise,
                 float* __restrict__ out) {
  __shared__ bf16_t As0[64 * LDK2], As1[64 * LDK2];
  __shared__ bf16_t Bs0[32 * LDK2], Bs1[32 * LDK2];
  __shared__ float lgbuf[64][17];
  __shared__ float red[8];
  int tid = threadIdx.x;
  int lane = tid & 63, wave = tid >> 6;
  int wr = wave & 3, wc = wave >> 2;          // 4x2 wave grid
  int n0 = blockIdx.x * 16, m0 = blockIdx.y * 64;
  int arow = tid >> 3, akg8 = (tid & 7) * 8;
  int bn = tid & 31, bkq4 = (tid >> 5) * 4;
  int fm = lane & 15, kq = lane >> 4;
  int arr = (wr * 16 + fm) * LDK2 + kq * 8;
  int brr = (wc * 16 + fm) * LDK2 + kq * 8;

  const bf16_t* Ap = A + (size_t)(m0 + arow) * 2048 + akg8;
  // dual-panel column map: bn 0..15 -> me cols n0+bn, bn 16..31 -> lg cols 1024+n0+bn-16
  int bcol = n0 + (bn & 15) + ((bn >> 4) << 10);
  const float* Wp0 = W + (size_t)bkq4 * 2048 + bcol;

  f32x4 acc = (f32x4)0.0f;   // wc=0: mu_eps frag; wc=1: ln_sig frag
  g512_loop<32>(Ap, Wp0, As0, As1, Bs0, Bs1, arow, akg8, bn, bkq4, arr, brr, acc);

  // pair (me, lg) across the wc halves through LDS
  if (wc == 1) {
#pragma unroll
    for (int e = 0; e < 4; ++e)
      lgbuf[wr * 16 + kq * 4 + e][fm] = acc[e];
  }
  __syncthreads();

  float lsum = 0.0f;
  if (wc == 0) {
    int d = n0 + fm;
    float bme = b2[d], blg = b2[1024 + d];
#pragma unroll
    for (int e = 0; e < 4; ++e) {
      int row = m0 + wr * 16 + kq * 4 + e;
      float tv = t[row];
      float om = exp2f(2.0f * tv * L2S);       // 1-gamma
      float gamma = 1.0f - om;
      float rq = sqrtf(om / gamma);
      float w = 1.0f / om;                     // SIGMA1^(-2t)
      bool lowt = tv < 1e-10f;
      float me = acc[e] + bme;
      float lg = lgbuf[wr * 16 + kq * 4 + e][fm] + blg;
      float xs = x[(size_t)row * 1024 + d], ns = noise[(size_t)row * 1024 + d];

      float mu_x = xs + om * ns - rq * me;     // mu/gamma - r*mu_eps
      float sig = rq * __expf(lg);
      if (lowt) { mu_x = 0.f; sig = 1.f; }
      float invs = 0.70710678118654752f / sig; // 1/(sigma*sqrt(2))
      float a = invs * 0.015625f;              // z step per k
      float c0 = (1.f + mu_x) * invs;          // z_k = a*k - c0
      // window |z|<3.5 for the k=1..126 interior sum; saturated tails exact
      float m64 = 64.f * (1.f + mu_x);
      float wdt = 316.78383797157331f * sig;   // 3.5/a = 224*sqrt(2)*sig
      float lo = m64 - wdt, hi = m64 + wdt;
      int klo = (lo < 1.f) ? 1 : ((lo > 126.f) ? 127 : (int)ceilf(lo));
      int khi = (hi < 1.f) ? 0 : ((hi > 126.f) ? 126 : (int)floorf(hi));
      float ss = (float)(126 - khi) - (float)(klo - 1);
      if (khi >= klo) {
        if (a <= 1.0f) {
          // Euler-Maclaurin midpoint: sum ~ (1/a)[G(zb)-G(za)] - (a/(12 sqrt(pi)))(eb-ea)
          float za = fmaf(a, (float)klo - 0.5f, -c0);
          float zb = fmaf(a, (float)khi + 0.5f, -c0);
          const float ISP = 0.56418958354775628f;  // 1/sqrt(pi)
          float ea = __expf(-za * za), eb = __expf(-zb * zb);
          float Ga = fmaf(za, erf_f(za), ISP * ea);
          float Gb = fmaf(zb, erf_f(zb), ISP * eb);
          float S = (Gb - Ga) * __builtin_amdgcn_rcpf(a)
                  - a * 0.047015889f * (eb - ea);  // 1/(12*sqrt(pi))
          ss += S;
        } else {
          for (int k = klo; k <= khi; ++k) ss += erf_f(fmaf(a, (float)k, -c0));
        }
      }
      float z127 = fmaf(a, 127.f, -c0);
      float pO = fmaf(0.48828125f, 1.f + erf_f(z127),
                      fmaf(-0.0078125f, ss, -0.984375f));
      float df = xs - pO;
      lsum += w * df * df;
    }
  }
#pragma unroll
  for (int off = 32; off > 0; off >>= 1) lsum += __shfl_down(lsum, off, 64);
  if ((tid & 63) == 0) red[wave] = lsum;
  __syncthreads();
  if (tid == 0) {
    const float SCALE = 3.9120230054281461f / 262144.0f;  // -ln(0.02)/(B*D)
    atomicAdd(out, (red[0] + red[1] + red[2] + red[3] +
                    red[4] + red[5] + red[6] + red[7]) * SCALE);
  }
}

extern "C" void kernel_launch(void* const* d_in, const int* in_sizes, int n_in,
                              void* d_out, int out_size, void* d_ws, size_t ws_size,
                              hipStream_t stream) {
  const float* x     = (const float*)d_in[0];
  const float* t     = (const float*)d_in[1];
  const float* noise = (const float*)d_in[2];
  const float* W1    = (const float*)d_in[3];
  const float* b1    = (const float*)d_in[4];
  const float* W2    = (const float*)d_in[5];
  const float* b2    = (const float*)d_in[6];
  float* out = (float*)d_out;

  // ws layout (1.5 MB live): A1 bf16 512 KB, h bf16 1 MB
  char* ws = (char*)d_ws;
  bf16_t* A1 = (bf16_t*)ws;
  bf16_t* h  = (bf16_t*)(ws + 524288);

  prep_k<<<256, 256, 0, stream>>>(x, noise, t, A1, out);
  gemm1h_k<<<dim3(64, 4), 512, 0, stream>>>(A1, W1, b1, t, h);
  gemm2loss_k<<<dim3(64, 4), 512, 0, stream>>>(h, W2, b2, t, x, noise, out);
}